// Round 9
// baseline (25.355 us; speedup 1.0000x reference)
//
#include <hip/hip_runtime.h>

#define B_ 2
#define H_ 352
#define W_ 1216
#define HW_ (H_ * W_)      // 428032
#define K_ 9
#define TW 64              // tile width
#define TH 16              // tile height (two 8-row phases)
#define SOFF 8             // halo margin
#define SR (TH + 2 * SOFF) // 32 staged rows
#define SC (TW + 2 * SOFF) // 80 staged cols
#define NBX (W_ / TW)      // 19
#define NBY (H_ / TH)      // 22
#define NBLK (B_ * NBX * NBY)  // 836 blocks x 512 threads
#define NV4 (SR * (SC / 4))    // 640 float4 stage elements

typedef float v4 __attribute__((ext_vector_type(4)));

__device__ __forceinline__ float dcn_taps(
    const float* __restrict__ sm, const float* __restrict__ dpt,
    int oy, int ox, int y, int x,
    const float* ody, const float* odx, const float* cf)
{
    float acc = 0.f;
#pragma unroll
    for (int k = 0; k < K_; ++k) {
        const float py = (float)(y + (k / 3) - 1) + ody[k];
        const float px = (float)(x + (k % 3) - 1) + odx[k];
        const float y0f = floorf(py);
        const float x0f = floorf(px);
        const float fy = py - y0f;
        const float fx = px - x0f;
        const int yi0 = (int)y0f, xi0 = (int)x0f;

        const int ly = yi0 - oy;           // need [0, SR-2]
        const int lx = xi0 - ox;           // need [0, SC-2]
        float v00, v01, v10, v11;
        if (__builtin_expect((unsigned)ly <= (SR - 2) && (unsigned)lx <= (SC - 2), 1)) {
            const float* s = sm + ly * SC + lx;
            v00 = s[0];
            v01 = s[1];
            v10 = s[SC];
            v11 = s[SC + 1];
        } else {
            // ultra-rare fallback (|offset| > ~7): zero-padded global gather
            const int yi1 = yi0 + 1, xi1 = xi0 + 1;
            const bool vy0 = (unsigned)yi0 < (unsigned)H_;
            const bool vy1 = (unsigned)yi1 < (unsigned)H_;
            const bool vx0 = (unsigned)xi0 < (unsigned)W_;
            const bool vx1 = (unsigned)xi1 < (unsigned)W_;
            const int r0 = yi0 * W_;
            const int r1 = r0 + W_;
            v00 = (vy0 && vx0) ? dpt[r0 + xi0] : 0.f;
            v01 = (vy0 && vx1) ? dpt[r0 + xi1] : 0.f;
            v10 = (vy1 && vx0) ? dpt[r1 + xi0] : 0.f;
            v11 = (vy1 && vx1) ? dpt[r1 + xi1] : 0.f;
        }

        const float a  = fmaf(fx, v01 - v00, v00);
        const float c  = fmaf(fx, v11 - v10, v10);
        const float val = fmaf(fy, c - a, a);
        acc = fmaf(cf[k], val, acc);
    }
    return acc;
}

__global__ __launch_bounds__(512) void dcn_post_kernel(
    const float* __restrict__ depth,
    const float* __restrict__ weight,
    const float* __restrict__ offset,
    const float* __restrict__ wtap,
    const float* __restrict__ bias,
    float* __restrict__ out)
{
    __shared__ float sm[SR * SC];   // 10240 B

    const int bid = blockIdx.x;
    const int b   = bid / (NBX * NBY);
    const int r2  = bid - b * (NBX * NBY);
    const int by  = r2 / NBX;
    const int bx  = r2 - by * NBX;
    const int tid = threadIdx.x;
    const int tx  = tid & (TW - 1);    // 0..63
    const int ty  = tid >> 6;          // 0..7

    const int y0 = by * TH;
    const int x  = bx * TW + tx;
    const int yA = y0 + ty;            // phase A row
    const int yB = yA + 8;             // phase B row
    const int oy = y0 - SOFF;
    const int ox = bx * TW - SOFF;
    const int pA = yA * W_ + x;
    const int pB = pA + 8 * W_;

    const float* __restrict__ dpt = depth + b * HW_;

    // ---- stage 32x80 depth halo into LDS via predicated float4 ----
    {
        const int i = tid;
        const int r  = i / (SC / 4);
        const int c4 = (i - r * (SC / 4)) * 4;
        const int gy = oy + r;
        const int gx = ox + c4;
        v4 v = 0.f;
        if ((unsigned)gy < (unsigned)H_ && (unsigned)gx < (unsigned)W_)
            v = *reinterpret_cast<const v4*>(dpt + gy * W_ + gx);
        *reinterpret_cast<v4*>(sm + r * SC + c4) = v;
    }
    if (tid < NV4 - 512) {
        const int i = tid + 512;
        const int r  = i / (SC / 4);
        const int c4 = (i - r * (SC / 4)) * 4;
        const int gy = oy + r;
        const int gx = ox + c4;
        v4 v = 0.f;
        if ((unsigned)gy < (unsigned)H_ && (unsigned)gx < (unsigned)W_)
            v = *reinterpret_cast<const v4*>(dpt + gy * W_ + gx);
        *reinterpret_cast<v4*>(sm + r * SC + c4) = v;
    }

    // ---- prefetch phase-A streams (latency overlaps staging + barrier) ----
    const float bv = bias[0];
    float wt[K_];
#pragma unroll
    for (int k = 0; k < K_; ++k) wt[k] = wtap[k];

    const float* obaseA = offset + (size_t)b * 2 * K_ * HW_ + pA;
    float odyA[K_], odxA[K_];
#pragma unroll
    for (int k = 0; k < K_; ++k) {
        odyA[k] = obaseA[(2 * k) * HW_];
        odxA[k] = obaseA[(2 * k + 1) * HW_];
    }
    const float* wbaseA = weight + (size_t)b * K_ * HW_ + pA;
    float cfA[K_];
    float mA = 0.f;
#pragma unroll
    for (int k = 0; k < K_; ++k) {
        cfA[k] = wbaseA[k * HW_];
        mA += cfA[k];
    }
    mA *= (1.f / 9.f);
#pragma unroll
    for (int k = 0; k < K_; ++k) cfA[k] = (cfA[k] - mA) * wt[k];

    __syncthreads();   // halo + A streams complete

    // ---- issue phase-B streams NOW: latency hides under phase-A compute ----
    const float* obaseB = offset + (size_t)b * 2 * K_ * HW_ + pB;
    float odyB[K_], odxB[K_], wgB[K_];
#pragma unroll
    for (int k = 0; k < K_; ++k) {
        odyB[k] = obaseB[(2 * k) * HW_];
        odxB[k] = obaseB[(2 * k + 1) * HW_];
    }
    const float* wbaseB = weight + (size_t)b * K_ * HW_ + pB;
#pragma unroll
    for (int k = 0; k < K_; ++k) wgB[k] = wbaseB[k * HW_];

    // ---- phase A compute + store (pure LDS/VALU; B loads in flight) ----
    {
        const float dvalA = sm[(ty + SOFF) * SC + (tx + SOFF)];
        const float accA = dcn_taps(sm, dpt, oy, ox, yA, x, odyA, odxA, cfA);
        out[b * HW_ + pA] = accA + bv + dvalA;
    }

    // ---- phase B: fold coefficients (waits on wgB), compute + store ----
    {
        float cfB[K_];
        float mB = 0.f;
#pragma unroll
        for (int k = 0; k < K_; ++k) mB += wgB[k];
        mB *= (1.f / 9.f);
#pragma unroll
        for (int k = 0; k < K_; ++k) cfB[k] = (wgB[k] - mB) * wt[k];

        const float dvalB = sm[(ty + 8 + SOFF) * SC + (tx + SOFF)];
        const float accB = dcn_taps(sm, dpt, oy, ox, yB, x, odyB, odxB, cfB);
        out[b * HW_ + pB] = accB + bv + dvalB;
    }
}

extern "C" void kernel_launch(void* const* d_in, const int* in_sizes, int n_in,
                              void* d_out, int out_size, void* d_ws, size_t ws_size,
                              hipStream_t stream) {
    const float* depth  = (const float*)d_in[0];
    const float* weight = (const float*)d_in[1];
    const float* offset = (const float*)d_in[2];
    const float* wtap   = (const float*)d_in[3];
    const float* bias   = (const float*)d_in[4];
    float* out = (float*)d_out;

    dim3 grid(NBLK), block(512);
    hipLaunchKernelGGL(dcn_post_kernel, grid, block, 0, stream,
                       depth, weight, offset, wtap, bias, out);
}